// Round 1
// baseline (1405.949 us; speedup 1.0000x reference)
//
#include <hip/hip_runtime.h>
#include <math.h>

#define B_ 8
#define C_ 128
#define O3_ 384
#define H_ 128
#define W_ 128
#define L_ 16384
#define NS_ 32
#define MAXP_ 2304

// ---------------------------------------------------------------------------
// Generic small-K GEMM over positions: Y[b][o][l] = sum_k W[o][k] * X[b][k][l]
// MODE 0: plain
// MODE 1: X = Xa+Xb (sxy); y = gelu(acc+bias[o]) * (E0[o][l]+E1[o][l])
// MODE 2: y = acc + bias[o]
// MODE 3: y = acc + bias[o] + E0[b][o][l]
// ---------------------------------------------------------------------------
template<int KD, int MODE>
__global__ __launch_bounds__(256) void gemm_k(
    const float* __restrict__ Wt, const float* __restrict__ bias,
    const float* __restrict__ Xa, const float* __restrict__ Xb,
    const float* __restrict__ E0, const float* __restrict__ E1,
    float* __restrict__ Y)
{
    __shared__ float sW[32][68];
    __shared__ float sX[32][128];
    const int tid = threadIdx.x;
    const int tx = tid & 15, ty = tid >> 4;
    const int lB = blockIdx.x * 128;
    const int oB = blockIdx.y * 64;
    const int Mtot = gridDim.y * 64;
    const int b = blockIdx.z;
    const size_t xbase = (size_t)b * KD * L_ + lB;

    float acc[4][8];
#pragma unroll
    for (int i = 0; i < 4; i++)
#pragma unroll
        for (int j = 0; j < 8; j++) acc[i][j] = 0.f;

    for (int kc = 0; kc < KD; kc += 32) {
#pragma unroll
        for (int i = 0; i < 16; i++) {
            int id = tid + i * 256;
            int kk = id >> 7, l = id & 127;
            size_t g = xbase + (size_t)(kc + kk) * L_ + l;
            float v = Xa[g];
            if constexpr (MODE == 1) v += Xb[g];
            sX[kk][l] = v;
        }
#pragma unroll
        for (int i = 0; i < 8; i++) {
            int id = tid + i * 256;
            int o = id >> 5, kk = id & 31;
            sW[kk][o] = Wt[(size_t)(oB + o) * KD + kc + kk];
        }
        __syncthreads();
        for (int kk = 0; kk < 32; kk++) {
            const float4 wv = *reinterpret_cast<const float4*>(&sW[kk][ty * 4]);
            const float4 x0 = *reinterpret_cast<const float4*>(&sX[kk][tx * 8]);
            const float4 x1 = *reinterpret_cast<const float4*>(&sX[kk][tx * 8 + 4]);
            float w4[4] = {wv.x, wv.y, wv.z, wv.w};
            float x8[8] = {x0.x, x0.y, x0.z, x0.w, x1.x, x1.y, x1.z, x1.w};
#pragma unroll
            for (int i = 0; i < 4; i++)
#pragma unroll
                for (int j = 0; j < 8; j++)
                    acc[i][j] = fmaf(w4[i], x8[j], acc[i][j]);
        }
        __syncthreads();
    }

#pragma unroll
    for (int i = 0; i < 4; i++) {
        const int o = oB + ty * 4 + i;
        float bv = 0.f;
        if constexpr (MODE == 1 || MODE == 2 || MODE == 3) bv = bias[o];
        const size_t ybase = ((size_t)b * Mtot + o) * L_ + lB + tx * 8;
        const size_t ebase = ((size_t)b * C_ + o) * L_ + lB + tx * 8; // valid when Mtot==C_
        float v[8];
#pragma unroll
        for (int j = 0; j < 8; j++) {
            float a = acc[i][j] + bv;
            if constexpr (MODE == 1) {
                float sxy = E0[ebase + j] + E1[ebase + j];
                a = 0.5f * a * (1.0f + erff(a * 0.70710678118654752f)) * sxy;
            }
            if constexpr (MODE == 3) {
                a += E0[ebase + j];
            }
            v[j] = a;
        }
        float4 r0 = {v[0], v[1], v[2], v[3]};
        float4 r1 = {v[4], v[5], v[6], v[7]};
        *reinterpret_cast<float4*>(&Y[ybase]) = r0;
        *reinterpret_cast<float4*>(&Y[ybase + 4]) = r1;
    }
}

// ---------------------------------------------------------------------------
// Depthwise 3x3 SAME conv (cross-correlation, zero pad), per-channel weights
// ---------------------------------------------------------------------------
__global__ __launch_bounds__(256) void dwconv_k(const float* __restrict__ in,
    const float* __restrict__ wdw, float* __restrict__ outp)
{
    __shared__ float tile[4][130];
    const int ch = blockIdx.y, b = blockIdx.z;
    const int y0 = blockIdx.x * 2;
    const int tid = threadIdx.x;
    const size_t base = ((size_t)b * O3_ + ch) * L_;
    for (int id = tid; id < 520; id += 256) {
        int r = id / 130, cc = id - r * 130;
        int gy = y0 - 1 + r, gx = cc - 1;
        float v = 0.f;
        if (gy >= 0 && gy < H_ && gx >= 0 && gx < W_) v = in[base + (size_t)gy * W_ + gx];
        tile[r][cc] = v;
    }
    __syncthreads();
    const int ty = tid >> 7, tx = tid & 127;
    const float* wp = wdw + ch * 9;
    float s =
        tile[ty + 0][tx + 0] * wp[0] + tile[ty + 0][tx + 1] * wp[1] + tile[ty + 0][tx + 2] * wp[2] +
        tile[ty + 1][tx + 0] * wp[3] + tile[ty + 1][tx + 1] * wp[4] + tile[ty + 1][tx + 2] * wp[5] +
        tile[ty + 2][tx + 0] * wp[6] + tile[ty + 2][tx + 1] * wp[7] + tile[ty + 2][tx + 2] * wp[8];
    outp[base + (size_t)(y0 + ty) * W_ + tx] = s;
}

// ---------------------------------------------------------------------------
// Per-channel mean of q (channels 0..127 of dw output) over batch+length
// ---------------------------------------------------------------------------
__global__ __launch_bounds__(256) void chmean_k(const float* __restrict__ dw, double* __restrict__ cm)
{
    const int c = blockIdx.x, tid = threadIdx.x;
    double s = 0.0;
    for (int b = 0; b < B_; b++) {
        const float* row = dw + ((size_t)b * O3_ + c) * L_;
        for (int l = tid; l < L_; l += 256) s += (double)row[l];
    }
    __shared__ double sm[256];
    sm[tid] = s; __syncthreads();
    for (int st = 128; st > 0; st >>= 1) {
        if (tid < st) sm[tid] += sm[tid + st];
        __syncthreads();
    }
    if (tid == 0) cm[c] = sm[0] / (double)((size_t)B_ * L_);
}

// stable argsort(-mean): idx[rank] = channel
__global__ void rank_k(const double* __restrict__ cm, int* __restrict__ idxp)
{
    __shared__ double s[128];
    const int t = threadIdx.x;
    s[t] = cm[t]; __syncthreads();
    const double mv = s[t];
    int r = 0;
    for (int j = 0; j < 128; j++) {
        double o = s[j];
        if (o > mv || (o == mv && j < t)) r++;
    }
    idxp[r] = t;
}

// reciprocal L2 norms of sorted q,k rows
__global__ __launch_bounds__(256) void norms_k(const float* __restrict__ dw, const int* __restrict__ idxp,
    float* __restrict__ rq, float* __restrict__ rk)
{
    const int r = blockIdx.x, b = blockIdx.y, tid = threadIdx.x;
    const int c = idxp[r];
    const float* qrow = dw + ((size_t)b * O3_ + c) * L_;
    const float* krow = dw + ((size_t)b * O3_ + 128 + c) * L_;
    float sq = 0.f, sk = 0.f;
    for (int l = tid; l < L_; l += 256) {
        float a = qrow[l]; sq = fmaf(a, a, sq);
        float e = krow[l]; sk = fmaf(e, e, sk);
    }
    __shared__ float smq[256], smk[256];
    smq[tid] = sq; smk[tid] = sk; __syncthreads();
    for (int st = 128; st > 0; st >>= 1) {
        if (tid < st) { smq[tid] += smq[tid + st]; smk[tid] += smk[tid + st]; }
        __syncthreads();
    }
    if (tid == 0) {
        rq[b * 128 + r] = 1.f / fmaxf(sqrtf(smq[0]), 1e-12f);
        rk[b * 128 + r] = 1.f / fmaxf(sqrtf(smk[0]), 1e-12f);
    }
}

// ---------------------------------------------------------------------------
// Partial raw scores S[c][d] = sum_l q[c,l]*k[d,l] over one L-split
// ---------------------------------------------------------------------------
template<int G>
__global__ __launch_bounds__(256) void score_k(const float* __restrict__ dw, const int* __restrict__ idxp,
    int start, int gi, float* __restrict__ spart)
{
    constexpr int TS = G / 16;
    const int split = blockIdx.x, b = blockIdx.y;
    const int tid = threadIdx.x, tx = tid & 15, ty = tid >> 4;
    __shared__ float sQ[G][66];
    __shared__ float sK[G][66];
    __shared__ int sc[G];
    if (tid < G) sc[tid] = idxp[start + tid];
    __syncthreads();

    float acc[TS][TS];
#pragma unroll
    for (int i = 0; i < TS; i++)
#pragma unroll
        for (int j = 0; j < TS; j++) acc[i][j] = 0.f;

    const int l0 = split * (L_ / NS_);
    constexpr int LPT = (G * 64) / 256;
    for (int chk = 0; chk < L_ / NS_; chk += 64) {
#pragma unroll
        for (int i = 0; i < LPT; i++) {
            int id = tid + i * 256;
            int row = id >> 6, lc = id & 63;
            size_t base = ((size_t)b * O3_ + sc[row]) * L_ + l0 + chk + lc;
            sQ[row][lc] = dw[base];
            sK[row][lc] = dw[base + (size_t)128 * L_];
        }
        __syncthreads();
#pragma unroll
        for (int kk = 0; kk < 64; kk++) {
            float qv[TS], kv[TS];
#pragma unroll
            for (int j = 0; j < TS; j++) { qv[j] = sQ[ty * TS + j][kk]; kv[j] = sK[tx * TS + j][kk]; }
#pragma unroll
            for (int i = 0; i < TS; i++)
#pragma unroll
                for (int j = 0; j < TS; j++)
                    acc[i][j] = fmaf(qv[i], kv[j], acc[i][j]);
        }
        __syncthreads();
    }
    float* op = spart + (((size_t)(b * 4 + gi)) * NS_ + split) * MAXP_;
#pragma unroll
    for (int i = 0; i < TS; i++)
#pragma unroll
        for (int j = 0; j < TS; j++)
            op[(ty * TS + i) * G + tx * TS + j] = acc[i][j];
}

// reduce partials, scale by rq*rk*temp, softmax rows -> attn
__global__ __launch_bounds__(256) void softmax_k(const float* __restrict__ spart,
    const float* __restrict__ rq, const float* __restrict__ rk,
    const float* __restrict__ temp, float* __restrict__ attn)
{
    const int gi = blockIdx.x, b = blockIdx.y;
    const int g = (gi == 0) ? 16 : (gi == 3 ? 48 : 32);
    const int start = (gi == 0) ? 0 : (gi == 1 ? 16 : (gi == 2 ? 48 : 80));
    __shared__ float S[MAXP_];
    const float tv = temp[gi];
    for (int p = threadIdx.x; p < g * g; p += 256) {
        float s = 0.f;
        const float* sp = spart + ((size_t)(b * 4 + gi)) * NS_ * MAXP_ + p;
        for (int k = 0; k < NS_; k++) s += sp[(size_t)k * MAXP_];
        int cc = p / g, dd = p - cc * g;
        S[p] = s * rq[b * 128 + start + cc] * rk[b * 128 + start + dd] * tv;
    }
    __syncthreads();
    const int wv = threadIdx.x >> 6, lane = threadIdx.x & 63;
    for (int r = wv; r < g; r += 4) {
        float val = (lane < g) ? S[r * g + lane] : -1e30f;
        float mx = val;
        for (int m = 32; m > 0; m >>= 1) mx = fmaxf(mx, __shfl_xor(mx, m));
        float e = (lane < g) ? expf(val - mx) : 0.f;
        float sum = e;
        for (int m = 32; m > 0; m >>= 1) sum += __shfl_xor(sum, m);
        if (lane < g) attn[((size_t)(b * 4 + gi)) * MAXP_ + r * g + lane] = e / sum;
    }
}

// out_all[c][l] = sum_d attn[c][d] * v[d][l]
template<int G>
__global__ __launch_bounds__(256) void av_k(const float* __restrict__ dw, const int* __restrict__ idxp,
    const float* __restrict__ attn, int start, int gi, float* __restrict__ outall)
{
    const int b = blockIdx.y;
    const int l = blockIdx.x * 256 + threadIdx.x;
    __shared__ float A[G * G];
    __shared__ int cv[G];
    if (threadIdx.x < G) cv[threadIdx.x] = 256 + idxp[start + threadIdx.x];
    for (int p = threadIdx.x; p < G * G; p += 256)
        A[p] = attn[((size_t)(b * 4 + gi)) * MAXP_ + p];
    __syncthreads();
    float acc[G];
#pragma unroll
    for (int c = 0; c < G; c++) acc[c] = 0.f;
    for (int d = 0; d < G; d++) {
        float vd = dw[((size_t)b * O3_ + cv[d]) * L_ + l];
#pragma unroll
        for (int c = 0; c < G; c++)
            acc[c] = fmaf(A[c * G + d], vd, acc[c]);
    }
    for (int c = 0; c < G; c++)
        outall[((size_t)b * C_ + start + c) * L_ + l] = acc[c];
}

// tc = qn + kn ; gm[b][r] = mean_l(tc)
__global__ __launch_bounds__(256) void tc_k(const float* __restrict__ dw, const int* __restrict__ idxp,
    const float* __restrict__ rq, const float* __restrict__ rk,
    float* __restrict__ tc, float* __restrict__ gm)
{
    const int r = blockIdx.x, b = blockIdx.y, tid = threadIdx.x;
    const int c = idxp[r];
    const float aq = rq[b * 128 + r], ak = rk[b * 128 + r];
    const float4* qr = reinterpret_cast<const float4*>(dw + ((size_t)b * O3_ + c) * L_);
    const float4* kr = reinterpret_cast<const float4*>(dw + ((size_t)b * O3_ + 128 + c) * L_);
    float4* tr = reinterpret_cast<float4*>(tc + ((size_t)b * C_ + r) * L_);
    float s = 0.f;
    for (int i = tid; i < L_ / 4; i += 256) {
        float4 q4 = qr[i], k4 = kr[i];
        float4 t;
        t.x = fmaf(q4.x, aq, k4.x * ak);
        t.y = fmaf(q4.y, aq, k4.y * ak);
        t.z = fmaf(q4.z, aq, k4.z * ak);
        t.w = fmaf(q4.w, aq, k4.w * ak);
        tr[i] = t;
        s += t.x + t.y + t.z + t.w;
    }
    __shared__ float sm[256];
    sm[tid] = s; __syncthreads();
    for (int st = 128; st > 0; st >>= 1) {
        if (tid < st) sm[tid] += sm[tid + st];
        __syncthreads();
    }
    if (tid == 0) gm[b * 128 + r] = sm[0] * (1.0f / L_);
}

// qv_cache = 0.9 * mean of tiled group means, broadcast over spatial
__global__ __launch_bounds__(256) void qvc_k(const float* __restrict__ gm, float* __restrict__ outq)
{
    const int cpos = blockIdx.x, b = blockIdx.y;
    const float* g = gm + b * 128;
    float v = g[cpos & 15] + g[16 + (cpos & 31)] + g[48 + (cpos & 31)];
    if (cpos < 96) v += g[80 + (cpos % 48)];
    v *= 0.225f; // 0.9 * (sum/4)
    float4 vv = {v, v, v, v};
    float4* op = reinterpret_cast<float4*>(outq + ((size_t)b * C_ + cpos) * L_);
    for (int i = threadIdx.x; i < L_ / 4; i += 256) op[i] = vv;
}

// ---------------------------------------------------------------------------
extern "C" void kernel_launch(void* const* d_in, const int* in_sizes, int n_in,
                              void* d_out, int out_size, void* d_ws, size_t ws_size,
                              hipStream_t stream)
{
    const float* x     = (const float*)d_in[0];
    const float* temp  = (const float*)d_in[1];
    const float* wqkv  = (const float*)d_in[2];
    const float* wdw   = (const float*)d_in[3];
    const float* wproj = (const float*)d_in[4];
    const float* wgate = (const float*)d_in[5];
    const float* bgate = (const float*)d_in[6];
    const float* wdown = (const float*)d_in[7];
    const float* bdown = (const float*)d_in[8];
    const float* wup   = (const float*)d_in[9];
    const float* bup   = (const float*)d_in[10];
    float* out = (float*)d_out;
    float* ws  = (float*)d_ws;

    // big buffers
    float* qkv = ws;                          // [8][384][16384]
    float* dw  = ws + 50331648ull;            // [8][384][16384]
    // qkv region is dead after dwconv; reuse:
    float* gated = ws;                        // [8][128][16384]
    float* mod1  = ws + 16777216ull;          // [8][64][16384]
    float* out2  = ws + 25165824ull;          // [8][128][16384]
    // small area inside dead qkv region (alive only after dwconv)
    double* cm  = (double*)(ws + 45000000ull);     // 128 doubles
    int*   idxp = (int*)(ws + 45000256ull);        // 128 ints
    float* rq   = ws + 45000384ull;                // 1024
    float* rk   = ws + 45001408ull;                // 1024
    float* gm   = ws + 45002432ull;                // 1024
    float* attn = ws + 45003456ull;                // 8*4*2304
    float* spart= ws + 45077184ull;                // 8*4*32*2304
    // out_all / tc live in d_out until consumed
    float* outall = out;                      // [8][128][16384]
    float* tc     = out + 16777216ull;        // [8][128][16384]

    // 1. qkv pointwise GEMM
    gemm_k<128, 0><<<dim3(128, 6, 8), 256, 0, stream>>>(wqkv, nullptr, x, nullptr, nullptr, nullptr, qkv);
    // 2. depthwise 3x3
    dwconv_k<<<dim3(64, 384, 8), 256, 0, stream>>>(qkv, wdw, dw);
    // 3. channel means of q + stable rank
    chmean_k<<<128, 256, 0, stream>>>(dw, cm);
    rank_k<<<1, 128, 0, stream>>>(cm, idxp);
    // 4. reciprocal norms
    norms_k<<<dim3(128, 8), 256, 0, stream>>>(dw, idxp, rq, rk);
    // 5. attention scores (partials) per group
    score_k<16><<<dim3(NS_, 8), 256, 0, stream>>>(dw, idxp, 0, 0, spart);
    score_k<32><<<dim3(NS_, 8), 256, 0, stream>>>(dw, idxp, 16, 1, spart);
    score_k<32><<<dim3(NS_, 8), 256, 0, stream>>>(dw, idxp, 48, 2, spart);
    score_k<48><<<dim3(NS_, 8), 256, 0, stream>>>(dw, idxp, 80, 3, spart);
    // 6. reduce + softmax
    softmax_k<<<dim3(4, 8), 256, 0, stream>>>(spart, rq, rk, temp, attn);
    // 7. attn @ v
    av_k<16><<<dim3(64, 8), 256, 0, stream>>>(dw, idxp, attn, 0, 0, outall);
    av_k<32><<<dim3(64, 8), 256, 0, stream>>>(dw, idxp, attn, 16, 1, outall);
    av_k<32><<<dim3(64, 8), 256, 0, stream>>>(dw, idxp, attn, 48, 2, outall);
    av_k<48><<<dim3(64, 8), 256, 0, stream>>>(dw, idxp, attn, 80, 3, outall);
    // 8. tc = qn+kn, group means
    tc_k<<<dim3(128, 8), 256, 0, stream>>>(dw, idxp, rq, rk, tc, gm);
    // 9. gate GEMM (+gelu, *sxy) — last reader of tc
    gemm_k<128, 1><<<dim3(128, 2, 8), 256, 0, stream>>>(wgate, bgate, outall, tc, outall, tc, gated);
    // 10. qv_cache fill (overwrites tc region of d_out)
    qvc_k<<<dim3(128, 8), 256, 0, stream>>>(gm, out + 16777216ull);
    // 11. down GEMM
    gemm_k<128, 2><<<dim3(128, 1, 8), 256, 0, stream>>>(wdown, bdown, gated, nullptr, nullptr, nullptr, mod1);
    // 12. up GEMM + residual
    gemm_k<64, 3><<<dim3(128, 2, 8), 256, 0, stream>>>(wup, bup, mod1, nullptr, outall, nullptr, out2);
    // 13. proj GEMM -> final output (overwrites outall region of d_out)
    gemm_k<128, 0><<<dim3(128, 2, 8), 256, 0, stream>>>(wproj, nullptr, out2, nullptr, nullptr, nullptr, out);
}

// Round 2
// 852.762 us; speedup vs baseline: 1.6487x; 1.6487x over previous
//
#include <hip/hip_runtime.h>
#include <math.h>

#define B_ 8
#define C_ 128
#define O3_ 384
#define H_ 128
#define W_ 128
#define L_ 16384
#define NS_ 64
#define MAXP_ 2304

// ---------------------------------------------------------------------------
// Pointwise GEMM over positions: Y[b][o][l] = sum_k W[o][k] * X[b][k][l]
// Tile: OT o x 128 l per block, acc[RO][8] per thread.
// MODE 0: plain
// MODE 1: y = gelu(acc+bias[o]) * E0[b][o][l]
// MODE 2: y = acc + bias[o]
// MODE 3: y = acc + bias[o] + E0[b][o][l]
// ---------------------------------------------------------------------------
template<int KD, int OT, int MODE>
__global__ __launch_bounds__(256) void gemm_k(
    const float* __restrict__ Wt, const float* __restrict__ bias,
    const float* __restrict__ Xa, const float* __restrict__ E0,
    float* __restrict__ Y)
{
    constexpr int RO = OT / 16;   // 8 (OT=128) or 4 (OT=64)
    __shared__ float sW[32][OT + 4];
    __shared__ float sX[32][128];
    const int tid = threadIdx.x;
    const int tx = tid & 15, ty = tid >> 4;
    const int lB = blockIdx.x * 128;
    const int oB = blockIdx.y * OT;
    const int Mtot = gridDim.y * OT;
    const int b = blockIdx.z;
    const size_t xbase = (size_t)b * KD * L_ + lB;

    float acc[RO][8];
#pragma unroll
    for (int i = 0; i < RO; i++)
#pragma unroll
        for (int j = 0; j < 8; j++) acc[i][j] = 0.f;

    for (int kc = 0; kc < KD; kc += 32) {
        // stage X tile: 32k x 128l, float4 per thread x4
#pragma unroll
        for (int p = 0; p < 4; p++) {
            int f4 = tid + p * 256;
            int kk = f4 >> 5, c4 = f4 & 31;
            float4 v = *reinterpret_cast<const float4*>(&Xa[xbase + (size_t)(kc + kk) * L_ + c4 * 4]);
            *reinterpret_cast<float4*>(&sX[kk][c4 * 4]) = v;
        }
        // stage W tile transposed: sW[kk][o]
#pragma unroll
        for (int p = 0; p < OT / 8; p++) {
            int id = tid + p * 256;
            int o = id >> 5, kk = id & 31;
            sW[kk][o] = Wt[(size_t)(oB + o) * KD + kc + kk];
        }
        __syncthreads();
#pragma unroll 8
        for (int kk = 0; kk < 32; kk++) {
            float xv[8], wv[8];
            *reinterpret_cast<float4*>(&xv[0]) = *reinterpret_cast<const float4*>(&sX[kk][tx * 4]);
            *reinterpret_cast<float4*>(&xv[4]) = *reinterpret_cast<const float4*>(&sX[kk][64 + tx * 4]);
            *reinterpret_cast<float4*>(&wv[0]) = *reinterpret_cast<const float4*>(&sW[kk][ty * 4]);
            if constexpr (RO == 8)
                *reinterpret_cast<float4*>(&wv[4]) = *reinterpret_cast<const float4*>(&sW[kk][64 + ty * 4]);
#pragma unroll
            for (int i = 0; i < RO; i++)
#pragma unroll
                for (int j = 0; j < 8; j++)
                    acc[i][j] = fmaf(wv[i], xv[j], acc[i][j]);
        }
        __syncthreads();
    }

#pragma unroll
    for (int i = 0; i < RO; i++) {
        const int oo = (i < 4) ? (ty * 4 + i) : (64 + ty * 4 + (i - 4));
        const int o = oB + oo;
        float bv = 0.f;
        if constexpr (MODE != 0) bv = bias[o];
#pragma unroll
        for (int hl = 0; hl < 2; hl++) {
            const int l = lB + hl * 64 + tx * 4;
            const size_t ybase = ((size_t)b * Mtot + o) * L_ + l;
            const size_t ebase = ((size_t)b * C_ + o) * L_ + l;
            float v[4];
#pragma unroll
            for (int j = 0; j < 4; j++) {
                float a = acc[i][hl * 4 + j] + bv;
                if constexpr (MODE == 1) {
                    float sxy = E0[ebase + j];
                    a = 0.5f * a * (1.0f + erff(a * 0.70710678118654752f)) * sxy;
                }
                if constexpr (MODE == 3) a += E0[ebase + j];
                v[j] = a;
            }
            float4 r = {v[0], v[1], v[2], v[3]};
            *reinterpret_cast<float4*>(&Y[ybase]) = r;
        }
    }
}

// ---------------------------------------------------------------------------
// Depthwise 3x3 SAME conv, 8 output rows per block
// ---------------------------------------------------------------------------
__global__ __launch_bounds__(256) void dwconv_k(const float* __restrict__ in,
    const float* __restrict__ wdw, float* __restrict__ outp)
{
    __shared__ float tile[10][130];
    const int ch = blockIdx.y, b = blockIdx.z;
    const int y0 = blockIdx.x * 8;
    const int tid = threadIdx.x;
    const size_t base = ((size_t)b * O3_ + ch) * L_;
    for (int id = tid; id < 1300; id += 256) {
        int r = id / 130, cc = id - r * 130;
        int gy = y0 - 1 + r, gx = cc - 1;
        float v = 0.f;
        if (gy >= 0 && gy < H_ && gx >= 0 && gx < W_) v = in[base + (size_t)gy * W_ + gx];
        tile[r][cc] = v;
    }
    __syncthreads();
    const float* wp = wdw + ch * 9;
    const float w0 = wp[0], w1 = wp[1], w2 = wp[2], w3 = wp[3], w4 = wp[4],
                w5 = wp[5], w6 = wp[6], w7 = wp[7], w8 = wp[8];
    const int tx = tid & 127, ty0 = tid >> 7;
#pragma unroll
    for (int rr = 0; rr < 4; rr++) {
        int r = ty0 + rr * 2;
        float s =
            tile[r + 0][tx + 0] * w0 + tile[r + 0][tx + 1] * w1 + tile[r + 0][tx + 2] * w2 +
            tile[r + 1][tx + 0] * w3 + tile[r + 1][tx + 1] * w4 + tile[r + 1][tx + 2] * w5 +
            tile[r + 2][tx + 0] * w6 + tile[r + 2][tx + 1] * w7 + tile[r + 2][tx + 2] * w8;
        outp[base + (size_t)(y0 + r) * W_ + tx] = s;
    }
}

// ---------------------------------------------------------------------------
// Per-(b,c): sum q, sum k, sum q^2, sum k^2 over L (fixed-order, deterministic)
// ---------------------------------------------------------------------------
__global__ __launch_bounds__(256) void sums_k(const float* __restrict__ dw,
    float* __restrict__ sumq, float* __restrict__ sumk,
    float* __restrict__ ssq, float* __restrict__ ssk)
{
    const int c = blockIdx.x, b = blockIdx.y, tid = threadIdx.x;
    const float4* qr = reinterpret_cast<const float4*>(dw + ((size_t)b * O3_ + c) * L_);
    const float4* kr = reinterpret_cast<const float4*>(dw + ((size_t)b * O3_ + 128 + c) * L_);
    float sq = 0.f, s2q = 0.f, sk = 0.f, s2k = 0.f;
    for (int i = tid; i < L_ / 4; i += 256) {
        float4 q4 = qr[i], k4 = kr[i];
        sq += (q4.x + q4.y) + (q4.z + q4.w);
        sk += (k4.x + k4.y) + (k4.z + k4.w);
        s2q += q4.x * q4.x + q4.y * q4.y + q4.z * q4.z + q4.w * q4.w;
        s2k += k4.x * k4.x + k4.y * k4.y + k4.z * k4.z + k4.w * k4.w;
    }
    __shared__ float sm[4][256];
    sm[0][tid] = sq; sm[1][tid] = sk; sm[2][tid] = s2q; sm[3][tid] = s2k;
    __syncthreads();
    for (int st = 128; st > 0; st >>= 1) {
        if (tid < st) {
            sm[0][tid] += sm[0][tid + st]; sm[1][tid] += sm[1][tid + st];
            sm[2][tid] += sm[2][tid + st]; sm[3][tid] += sm[3][tid + st];
        }
        __syncthreads();
    }
    if (tid == 0) {
        sumq[b * 128 + c] = sm[0][0]; sumk[b * 128 + c] = sm[1][0];
        ssq[b * 128 + c]  = sm[2][0]; ssk[b * 128 + c]  = sm[3][0];
    }
}

// combine: channel means (double, fixed order) -> stable rank; rq,rk; gm
__global__ void combine_k(const float* __restrict__ sumq, const float* __restrict__ sumk,
    const float* __restrict__ ssq, const float* __restrict__ ssk,
    int* __restrict__ idxp, float* __restrict__ rqc, float* __restrict__ rkc,
    float* __restrict__ gm)
{
    const int t = threadIdx.x; // 128
    __shared__ double cms[128];
    double s = 0.0;
    for (int b = 0; b < B_; b++) s += (double)sumq[b * 128 + t];
    cms[t] = s;
    float rqv[B_], rkv[B_];
    for (int b = 0; b < B_; b++) {
        rqv[b] = 1.f / fmaxf(sqrtf(ssq[b * 128 + t]), 1e-12f);
        rkv[b] = 1.f / fmaxf(sqrtf(ssk[b * 128 + t]), 1e-12f);
        rqc[b * 128 + t] = rqv[b];
        rkc[b * 128 + t] = rkv[b];
    }
    __syncthreads();
    const double mv = cms[t];
    int r = 0;
    for (int j = 0; j < 128; j++) {
        double o = cms[j];
        if (o > mv || (o == mv && j < t)) r++;
    }
    idxp[r] = t;
    for (int b = 0; b < B_; b++)
        gm[b * 128 + r] = (rqv[b] * sumq[b * 128 + t] + rkv[b] * sumk[b * 128 + t]) * (1.0f / L_);
}

// ---------------------------------------------------------------------------
// Partial raw scores S[c][d] = sum_l q[c,l]*k[d,l] over one L-split
// ---------------------------------------------------------------------------
template<int G>
__global__ __launch_bounds__(256) void score_k(const float* __restrict__ dw, const int* __restrict__ idxp,
    int start, int gi, float* __restrict__ spart)
{
    constexpr int TS = G / 16;
    const int split = blockIdx.x, b = blockIdx.y;
    const int tid = threadIdx.x, tx = tid & 15, ty = tid >> 4;
    __shared__ float sQ[G][66];
    __shared__ float sK[G][66];
    __shared__ int sc[G];
    if (tid < G) sc[tid] = idxp[start + tid];
    __syncthreads();

    float acc[TS][TS];
#pragma unroll
    for (int i = 0; i < TS; i++)
#pragma unroll
        for (int j = 0; j < TS; j++) acc[i][j] = 0.f;

    const int l0 = split * (L_ / NS_);
    constexpr int LPT = (G * 64) / 256;
    for (int chk = 0; chk < L_ / NS_; chk += 64) {
#pragma unroll
        for (int i = 0; i < LPT; i++) {
            int id = tid + i * 256;
            int row = id >> 6, lc = id & 63;
            size_t base = ((size_t)b * O3_ + sc[row]) * L_ + l0 + chk + lc;
            sQ[row][lc] = dw[base];
            sK[row][lc] = dw[base + (size_t)128 * L_];
        }
        __syncthreads();
#pragma unroll
        for (int kk = 0; kk < 64; kk++) {
            float qv[TS], kv[TS];
#pragma unroll
            for (int j = 0; j < TS; j++) { qv[j] = sQ[ty * TS + j][kk]; kv[j] = sK[tx * TS + j][kk]; }
#pragma unroll
            for (int i = 0; i < TS; i++)
#pragma unroll
                for (int j = 0; j < TS; j++)
                    acc[i][j] = fmaf(qv[i], kv[j], acc[i][j]);
        }
        __syncthreads();
    }
    float* op = spart + (((size_t)(b * 4 + gi)) * NS_ + split) * MAXP_;
#pragma unroll
    for (int i = 0; i < TS; i++)
#pragma unroll
        for (int j = 0; j < TS; j++)
            op[(ty * TS + i) * G + tx * TS + j] = acc[i][j];
}

// reduce partials, scale by rq*rk*temp, softmax rows -> attn
__global__ __launch_bounds__(256) void softmax_k(const float* __restrict__ spart,
    const float* __restrict__ rqc, const float* __restrict__ rkc, const int* __restrict__ idxp,
    const float* __restrict__ temp, float* __restrict__ attn)
{
    const int gi = blockIdx.x, b = blockIdx.y;
    const int g = (gi == 0) ? 16 : (gi == 3 ? 48 : 32);
    const int start = (gi == 0) ? 0 : (gi == 1 ? 16 : (gi == 2 ? 48 : 80));
    __shared__ float S[MAXP_];
    __shared__ int sidx[48];
    if (threadIdx.x < g) sidx[threadIdx.x] = idxp[start + threadIdx.x];
    __syncthreads();
    const float tv = temp[gi];
    for (int p = threadIdx.x; p < g * g; p += 256) {
        float s = 0.f;
        const float* sp = spart + ((size_t)(b * 4 + gi)) * NS_ * MAXP_ + p;
        for (int k = 0; k < NS_; k++) s += sp[(size_t)k * MAXP_];
        int cc = p / g, dd = p - cc * g;
        S[p] = s * rqc[b * 128 + sidx[cc]] * rkc[b * 128 + sidx[dd]] * tv;
    }
    __syncthreads();
    const int wv = threadIdx.x >> 6, lane = threadIdx.x & 63;
    for (int r = wv; r < g; r += 4) {
        float val = (lane < g) ? S[r * g + lane] : -1e30f;
        float mx = val;
        for (int m = 32; m > 0; m >>= 1) mx = fmaxf(mx, __shfl_xor(mx, m));
        float e = (lane < g) ? expf(val - mx) : 0.f;
        float sum = e;
        for (int m = 32; m > 0; m >>= 1) sum += __shfl_xor(sum, m);
        if (lane < g) attn[((size_t)(b * 4 + gi)) * MAXP_ + r * g + lane] = e / sum;
    }
}

// out_all[c][l] = sum_d attn[c][d]*v[d][l]; also emit sxy = out_all + qn + kn
template<int G>
__global__ __launch_bounds__(256) void av_k(const float* __restrict__ dw, const int* __restrict__ idxp,
    const float* __restrict__ rqc, const float* __restrict__ rkc,
    const float* __restrict__ attn, int start, int gi,
    float* __restrict__ outall, float* __restrict__ sxy)
{
    const int b = blockIdx.y;
    const int l = blockIdx.x * 256 + threadIdx.x;
    __shared__ float A[G * G];
    __shared__ int cv[G];
    __shared__ float rqs[G], rks[G];
    if (threadIdx.x < G) {
        int c0 = idxp[start + threadIdx.x];
        cv[threadIdx.x] = c0;
        rqs[threadIdx.x] = rqc[b * 128 + c0];
        rks[threadIdx.x] = rkc[b * 128 + c0];
    }
    for (int p = threadIdx.x; p < G * G; p += 256)
        A[p] = attn[((size_t)(b * 4 + gi)) * MAXP_ + p];
    __syncthreads();
    float acc[G];
#pragma unroll
    for (int c = 0; c < G; c++) acc[c] = 0.f;
    for (int d = 0; d < G; d++) {
        float vd = dw[((size_t)b * O3_ + 256 + cv[d]) * L_ + l];
#pragma unroll
        for (int c = 0; c < G; c++)
            acc[c] = fmaf(A[c * G + d], vd, acc[c]);
    }
    for (int c = 0; c < G; c++) {
        float q = dw[((size_t)b * O3_ + cv[c]) * L_ + l];
        float k = dw[((size_t)b * O3_ + 128 + cv[c]) * L_ + l];
        size_t ob = ((size_t)b * C_ + start + c) * L_ + l;
        outall[ob] = acc[c];
        sxy[ob] = acc[c] + rqs[c] * q + rks[c] * k;
    }
}

// qv_cache = 0.9 * mean of tiled group means, broadcast over spatial
__global__ __launch_bounds__(256) void qvc_k(const float* __restrict__ gm, float* __restrict__ outq)
{
    const int cpos = blockIdx.x, b = blockIdx.y;
    const float* g = gm + b * 128;
    float v = g[cpos & 15] + g[16 + (cpos & 31)] + g[48 + (cpos & 31)];
    if (cpos < 96) v += g[80 + (cpos % 48)];
    v *= 0.225f; // 0.9 * (sum/4)
    float4 vv = {v, v, v, v};
    float4* op = reinterpret_cast<float4*>(outq + ((size_t)b * C_ + cpos) * L_);
    for (int i = threadIdx.x; i < L_ / 4; i += 256) op[i] = vv;
}

// ---------------------------------------------------------------------------
extern "C" void kernel_launch(void* const* d_in, const int* in_sizes, int n_in,
                              void* d_out, int out_size, void* d_ws, size_t ws_size,
                              hipStream_t stream)
{
    const float* x     = (const float*)d_in[0];
    const float* temp  = (const float*)d_in[1];
    const float* wqkv  = (const float*)d_in[2];
    const float* wdw   = (const float*)d_in[3];
    const float* wproj = (const float*)d_in[4];
    const float* wgate = (const float*)d_in[5];
    const float* bgate = (const float*)d_in[6];
    const float* wdown = (const float*)d_in[7];
    const float* bdown = (const float*)d_in[8];
    const float* wup   = (const float*)d_in[9];
    const float* bup   = (const float*)d_in[10];
    float* out = (float*)d_out;
    float* ws  = (float*)d_ws;

    // big buffers
    float* qkv = ws;                          // [8][384][16384]
    float* dw  = ws + 50331648ull;            // [8][384][16384]
    // qkv region dead after dwconv; reuse:
    float* gated = ws;                        // [8][128][16384]
    float* mod1  = ws + 16777216ull;          // [8][64][16384]
    float* out2  = ws + 25165824ull;          // [8][128][16384] (ends 41943040)
    // small buffers inside dead qkv region
    float* sumq = ws + 44500000ull;           // 1024
    float* sumk = ws + 44501024ull;
    float* ssq  = ws + 44502048ull;
    float* ssk  = ws + 44503072ull;
    float* rqc  = ws + 44504096ull;
    float* rkc  = ws + 44505120ull;
    float* gm   = ws + 44506144ull;
    double* cmd = (double*)(ws + 44508000ull); (void)cmd;
    int*   idxp = (int*)(ws + 44510000ull);
    float* attn = ws + 45003456ull;           // 8*4*2304
    float* spart= ws + 45077184ull;           // 8*4*64*2304 (ends 49795776)
    // out_all / sxy live in d_out until consumed
    float* outall = out;                      // [8][128][16384]
    float* sxy    = out + 16777216ull;        // [8][128][16384]

    // 1. qkv pointwise GEMM
    gemm_k<128, 128, 0><<<dim3(128, 3, 8), 256, 0, stream>>>(wqkv, nullptr, x, nullptr, qkv);
    // 2. depthwise 3x3
    dwconv_k<<<dim3(16, 384, 8), 256, 0, stream>>>(qkv, wdw, dw);
    // 3. per-(b,c) sums + combine/rank
    sums_k<<<dim3(128, 8), 256, 0, stream>>>(dw, sumq, sumk, ssq, ssk);
    combine_k<<<1, 128, 0, stream>>>(sumq, sumk, ssq, ssk, idxp, rqc, rkc, gm);
    // 4. attention scores (partials) per group
    score_k<16><<<dim3(NS_, 8), 256, 0, stream>>>(dw, idxp, 0, 0, spart);
    score_k<32><<<dim3(NS_, 8), 256, 0, stream>>>(dw, idxp, 16, 1, spart);
    score_k<32><<<dim3(NS_, 8), 256, 0, stream>>>(dw, idxp, 48, 2, spart);
    score_k<48><<<dim3(NS_, 8), 256, 0, stream>>>(dw, idxp, 80, 3, spart);
    // 5. reduce + softmax
    softmax_k<<<dim3(4, 8), 256, 0, stream>>>(spart, rqc, rkc, idxp, temp, attn);
    // 6. attn @ v (+ sxy epilogue)
    av_k<16><<<dim3(64, 8), 256, 0, stream>>>(dw, idxp, rqc, rkc, attn, 0, 0, outall, sxy);
    av_k<32><<<dim3(64, 8), 256, 0, stream>>>(dw, idxp, rqc, rkc, attn, 16, 1, outall, sxy);
    av_k<32><<<dim3(64, 8), 256, 0, stream>>>(dw, idxp, rqc, rkc, attn, 48, 2, outall, sxy);
    av_k<48><<<dim3(64, 8), 256, 0, stream>>>(dw, idxp, rqc, rkc, attn, 80, 3, outall, sxy);
    // 7. gate GEMM (+gelu * sxy) — last reader of sxy
    gemm_k<128, 128, 1><<<dim3(128, 1, 8), 256, 0, stream>>>(wgate, bgate, sxy, sxy, gated);
    // 8. qv_cache fill (overwrites sxy region of d_out)
    qvc_k<<<dim3(128, 8), 256, 0, stream>>>(gm, out + 16777216ull);
    // 9. down GEMM
    gemm_k<128, 64, 2><<<dim3(128, 1, 8), 256, 0, stream>>>(wdown, bdown, gated, nullptr, mod1);
    // 10. up GEMM + residual
    gemm_k<64, 128, 3><<<dim3(128, 1, 8), 256, 0, stream>>>(wup, bup, mod1, outall, out2);
    // 11. proj GEMM -> final output
    gemm_k<128, 128, 0><<<dim3(128, 1, 8), 256, 0, stream>>>(wproj, nullptr, out2, nullptr, out);
}

// Round 3
// 709.967 us; speedup vs baseline: 1.9803x; 1.2011x over previous
//
#include <hip/hip_runtime.h>
#include <math.h>

#define B_ 8
#define C_ 128
#define O3_ 384
#define H_ 128
#define W_ 128
#define L_ 16384
#define NS_ 64
#define MAXP_ 2304

typedef float f32x4 __attribute__((ext_vector_type(4)));
typedef short bf16x8 __attribute__((ext_vector_type(8)));

static __device__ __forceinline__ ushort f2bf(float f) {
    uint u = __float_as_uint(f);
    u += 0x7fffu + ((u >> 16) & 1u);
    return (ushort)(u >> 16);
}
static __device__ __forceinline__ float bf2f(ushort h) {
    return __uint_as_float(((uint)h) << 16);
}

// ---------------------------------------------------------------------------
// Transpose x [b][128 c][L] -> xT [b][L][128 c]
// ---------------------------------------------------------------------------
__global__ __launch_bounds__(256) void transp_k(const float* __restrict__ x, float* __restrict__ xT)
{
    __shared__ float t[32][33];
    const int b = blockIdx.z;
    const int c0 = blockIdx.y * 32, l0 = blockIdx.x * 32;
    const int tx = threadIdx.x & 31, ty = threadIdx.x >> 5;
#pragma unroll
    for (int i = 0; i < 4; i++) {
        int c = ty + i * 8;
        t[c][tx] = x[((size_t)b * C_ + c0 + c) * L_ + l0 + tx];
    }
    __syncthreads();
#pragma unroll
    for (int i = 0; i < 4; i++) {
        int l = ty + i * 8;
        xT[((size_t)b * L_ + l0 + l) * C_ + c0 + tx] = t[tx][l];
    }
}

// ---------------------------------------------------------------------------
// NT MFMA GEMM (bf16x3): Y[l][o] (or [o][l]) = sum_c Xa[b][l][c] * Wt[o][c]
// MODE 0: plain [l][o]   1: gelu(acc+bias)*E0 [l][o]   2: acc+bias [l][o]
// MODE 3: acc+bias+E0 [l][o]   4: plain, transposed store [o][l]
// ---------------------------------------------------------------------------
template<int KD, int OT, int MODE>
__global__ __launch_bounds__(256) void mgemm_k(
    const float* __restrict__ Wt, const float* __restrict__ bias,
    const float* __restrict__ Xa, const float* __restrict__ E0,
    float* __restrict__ Y)
{
    constexpr int NR = OT / 32;
    __shared__ short sAh[128][40];
    __shared__ short sAl[128][40];
    __shared__ short sBh[OT][40];
    __shared__ short sBl[OT][40];
    const int tid = threadIdx.x;
    const int lane = tid & 63;
    const int wid = tid >> 6;
    const int wr = wid >> 1, wc = wid & 1;
    const int lB = blockIdx.x * 128;
    const int oB = blockIdx.y * OT;
    const int ON = gridDim.y * OT;
    const int b = blockIdx.z;
    const int ln15 = lane & 15, lg = lane >> 4;

    f32x4 acc[4][NR];
#pragma unroll
    for (int m = 0; m < 4; m++)
#pragma unroll
        for (int n = 0; n < NR; n++)
#pragma unroll
            for (int r = 0; r < 4; r++) acc[m][n][r] = 0.f;

    for (int kc = 0; kc < KD; kc += 32) {
        // stage A: 128 l x 32 c (hi/lo bf16)
#pragma unroll
        for (int p = 0; p < 4; p++) {
            int f4 = tid + p * 256;
            int l = f4 >> 3, c4 = f4 & 7;
            float4 v = *reinterpret_cast<const float4*>(
                &Xa[((size_t)b * L_ + lB + l) * KD + kc + c4 * 4]);
            ushort h0 = f2bf(v.x), h1 = f2bf(v.y), h2 = f2bf(v.z), h3 = f2bf(v.w);
            ushort g0 = f2bf(v.x - bf2f(h0)), g1 = f2bf(v.y - bf2f(h1));
            ushort g2 = f2bf(v.z - bf2f(h2)), g3 = f2bf(v.w - bf2f(h3));
            uint* ah = reinterpret_cast<uint*>(&sAh[l][0]);
            uint* al = reinterpret_cast<uint*>(&sAl[l][0]);
            ah[c4 * 2 + 0] = (uint)h0 | ((uint)h1 << 16);
            ah[c4 * 2 + 1] = (uint)h2 | ((uint)h3 << 16);
            al[c4 * 2 + 0] = (uint)g0 | ((uint)g1 << 16);
            al[c4 * 2 + 1] = (uint)g2 | ((uint)g3 << 16);
        }
        // stage B: OT o x 32 c
#pragma unroll
        for (int p = 0; p < OT / 32; p++) {
            int f4 = tid + p * 256;
            int o = f4 >> 3, c4 = f4 & 7;
            float4 v = *reinterpret_cast<const float4*>(
                &Wt[(size_t)(oB + o) * KD + kc + c4 * 4]);
            ushort h0 = f2bf(v.x), h1 = f2bf(v.y), h2 = f2bf(v.z), h3 = f2bf(v.w);
            ushort g0 = f2bf(v.x - bf2f(h0)), g1 = f2bf(v.y - bf2f(h1));
            ushort g2 = f2bf(v.z - bf2f(h2)), g3 = f2bf(v.w - bf2f(h3));
            uint* bh = reinterpret_cast<uint*>(&sBh[o][0]);
            uint* bl = reinterpret_cast<uint*>(&sBl[o][0]);
            bh[c4 * 2 + 0] = (uint)h0 | ((uint)h1 << 16);
            bh[c4 * 2 + 1] = (uint)h2 | ((uint)h3 << 16);
            bl[c4 * 2 + 0] = (uint)g0 | ((uint)g1 << 16);
            bl[c4 * 2 + 1] = (uint)g2 | ((uint)g3 << 16);
        }
        __syncthreads();
        bf16x8 Ah[4], Al[4], Bh[NR], Bl[NR];
#pragma unroll
        for (int m = 0; m < 4; m++) {
            int row = wr * 64 + m * 16 + ln15;
            Ah[m] = *reinterpret_cast<const bf16x8*>(&sAh[row][lg * 8]);
            Al[m] = *reinterpret_cast<const bf16x8*>(&sAl[row][lg * 8]);
        }
#pragma unroll
        for (int n = 0; n < NR; n++) {
            int row = wc * (OT / 2) + n * 16 + ln15;
            Bh[n] = *reinterpret_cast<const bf16x8*>(&sBh[row][lg * 8]);
            Bl[n] = *reinterpret_cast<const bf16x8*>(&sBl[row][lg * 8]);
        }
#pragma unroll
        for (int m = 0; m < 4; m++)
#pragma unroll
            for (int n = 0; n < NR; n++) {
                acc[m][n] = __builtin_amdgcn_mfma_f32_16x16x32_bf16(Ah[m], Bh[n], acc[m][n], 0, 0, 0);
                acc[m][n] = __builtin_amdgcn_mfma_f32_16x16x32_bf16(Ah[m], Bl[n], acc[m][n], 0, 0, 0);
                acc[m][n] = __builtin_amdgcn_mfma_f32_16x16x32_bf16(Al[m], Bh[n], acc[m][n], 0, 0, 0);
            }
        __syncthreads();
    }

#pragma unroll
    for (int m = 0; m < 4; m++) {
        const int lg4 = lB + wr * 64 + m * 16 + lg * 4;
#pragma unroll
        for (int n = 0; n < NR; n++) {
            const int o = oB + wc * (OT / 2) + n * 16 + ln15;
            if constexpr (MODE == 4) {
                float4 r4 = {acc[m][n][0], acc[m][n][1], acc[m][n][2], acc[m][n][3]};
                *reinterpret_cast<float4*>(&Y[((size_t)b * ON + o) * L_ + lg4]) = r4;
            } else {
                float bv = (MODE != 0) ? bias[o] : 0.f;
#pragma unroll
                for (int r = 0; r < 4; r++) {
                    size_t yi = ((size_t)b * L_ + lg4 + r) * ON + o;
                    float a = acc[m][n][r] + bv;
                    if constexpr (MODE == 1)
                        a = 0.5f * a * (1.f + erff(a * 0.70710678118654752f)) * E0[yi];
                    if constexpr (MODE == 3) a += E0[yi];
                    Y[yi] = a;
                }
            }
        }
    }
}

// ---------------------------------------------------------------------------
// Depthwise 3x3 SAME conv on [b][c][l] layout, 8 output rows per block
// ---------------------------------------------------------------------------
__global__ __launch_bounds__(256) void dwconv_k(const float* __restrict__ in,
    const float* __restrict__ wdw, float* __restrict__ outp)
{
    __shared__ float tile[10][130];
    const int ch = blockIdx.y, b = blockIdx.z;
    const int y0 = blockIdx.x * 8;
    const int tid = threadIdx.x;
    const size_t base = ((size_t)b * O3_ + ch) * L_;
    for (int id = tid; id < 1300; id += 256) {
        int r = id / 130, cc = id - r * 130;
        int gy = y0 - 1 + r, gx = cc - 1;
        float v = 0.f;
        if (gy >= 0 && gy < H_ && gx >= 0 && gx < W_) v = in[base + (size_t)gy * W_ + gx];
        tile[r][cc] = v;
    }
    __syncthreads();
    const float* wp = wdw + ch * 9;
    const float w0 = wp[0], w1 = wp[1], w2 = wp[2], w3 = wp[3], w4 = wp[4],
                w5 = wp[5], w6 = wp[6], w7 = wp[7], w8 = wp[8];
    const int tx = tid & 127, ty0 = tid >> 7;
#pragma unroll
    for (int rr = 0; rr < 4; rr++) {
        int r = ty0 + rr * 2;
        float s =
            tile[r + 0][tx + 0] * w0 + tile[r + 0][tx + 1] * w1 + tile[r + 0][tx + 2] * w2 +
            tile[r + 1][tx + 0] * w3 + tile[r + 1][tx + 1] * w4 + tile[r + 1][tx + 2] * w5 +
            tile[r + 2][tx + 0] * w6 + tile[r + 2][tx + 1] * w7 + tile[r + 2][tx + 2] * w8;
        outp[base + (size_t)(y0 + r) * W_ + tx] = s;
    }
}

// ---------------------------------------------------------------------------
// Per-(b,c): sum q, sum k, sum q^2, sum k^2 over L (fixed order)
// ---------------------------------------------------------------------------
__global__ __launch_bounds__(256) void sums_k(const float* __restrict__ dw,
    float* __restrict__ sumq, float* __restrict__ sumk,
    float* __restrict__ ssq, float* __restrict__ ssk)
{
    const int c = blockIdx.x, b = blockIdx.y, tid = threadIdx.x;
    const float4* qr = reinterpret_cast<const float4*>(dw + ((size_t)b * O3_ + c) * L_);
    const float4* kr = reinterpret_cast<const float4*>(dw + ((size_t)b * O3_ + 128 + c) * L_);
    float sq = 0.f, s2q = 0.f, sk = 0.f, s2k = 0.f;
    for (int i = tid; i < L_ / 4; i += 256) {
        float4 q4 = qr[i], k4 = kr[i];
        sq += (q4.x + q4.y) + (q4.z + q4.w);
        sk += (k4.x + k4.y) + (k4.z + k4.w);
        s2q += q4.x * q4.x + q4.y * q4.y + q4.z * q4.z + q4.w * q4.w;
        s2k += k4.x * k4.x + k4.y * k4.y + k4.z * k4.z + k4.w * k4.w;
    }
    __shared__ float sm[4][256];
    sm[0][tid] = sq; sm[1][tid] = sk; sm[2][tid] = s2q; sm[3][tid] = s2k;
    __syncthreads();
    for (int st = 128; st > 0; st >>= 1) {
        if (tid < st) {
            sm[0][tid] += sm[0][tid + st]; sm[1][tid] += sm[1][tid + st];
            sm[2][tid] += sm[2][tid + st]; sm[3][tid] += sm[3][tid + st];
        }
        __syncthreads();
    }
    if (tid == 0) {
        sumq[b * 128 + c] = sm[0][0]; sumk[b * 128 + c] = sm[1][0];
        ssq[b * 128 + c]  = sm[2][0]; ssk[b * 128 + c]  = sm[3][0];
    }
}

// combine: channel means (double) -> stable rank; rq,rk; gm
__global__ void combine_k(const float* __restrict__ sumq, const float* __restrict__ sumk,
    const float* __restrict__ ssq, const float* __restrict__ ssk,
    int* __restrict__ idxp, float* __restrict__ rqc, float* __restrict__ rkc,
    float* __restrict__ gm)
{
    const int t = threadIdx.x; // 128
    __shared__ double cms[128];
    double s = 0.0;
    for (int b = 0; b < B_; b++) s += (double)sumq[b * 128 + t];
    cms[t] = s;
    float rqv[B_], rkv[B_];
    for (int b = 0; b < B_; b++) {
        rqv[b] = 1.f / fmaxf(sqrtf(ssq[b * 128 + t]), 1e-12f);
        rkv[b] = 1.f / fmaxf(sqrtf(ssk[b * 128 + t]), 1e-12f);
        rqc[b * 128 + t] = rqv[b];
        rkc[b * 128 + t] = rkv[b];
    }
    __syncthreads();
    const double mv = cms[t];
    int r = 0;
    for (int j = 0; j < 128; j++) {
        double o = cms[j];
        if (o > mv || (o == mv && j < t)) r++;
    }
    idxp[r] = t;
    for (int b = 0; b < B_; b++)
        gm[b * 128 + r] = (rqv[b] * sumq[b * 128 + t] + rkv[b] * sumk[b * 128 + t]) * (1.0f / L_);
}

// ---------------------------------------------------------------------------
// Partial raw scores S[c][d] = sum_l q[c,l]*k[d,l] over one L-split
// ---------------------------------------------------------------------------
template<int G>
__global__ __launch_bounds__(256) void score_k(const float* __restrict__ dw, const int* __restrict__ idxp,
    int start, int gi, float* __restrict__ spart)
{
    constexpr int TS = G / 16;
    const int split = blockIdx.x, b = blockIdx.y;
    const int tid = threadIdx.x, tx = tid & 15, ty = tid >> 4;
    __shared__ float sQ[G][66];
    __shared__ float sK[G][66];
    __shared__ int sc[G];
    if (tid < G) sc[tid] = idxp[start + tid];
    __syncthreads();

    float acc[TS][TS];
#pragma unroll
    for (int i = 0; i < TS; i++)
#pragma unroll
        for (int j = 0; j < TS; j++) acc[i][j] = 0.f;

    const int l0 = split * (L_ / NS_);
    constexpr int LPT = (G * 64) / 256;
    for (int chk = 0; chk < L_ / NS_; chk += 64) {
#pragma unroll
        for (int i = 0; i < LPT; i++) {
            int id = tid + i * 256;
            int row = id >> 6, lc = id & 63;
            size_t base = ((size_t)b * O3_ + sc[row]) * L_ + l0 + chk + lc;
            sQ[row][lc] = dw[base];
            sK[row][lc] = dw[base + (size_t)128 * L_];
        }
        __syncthreads();
#pragma unroll
        for (int kk = 0; kk < 64; kk++) {
            float qv[TS], kv[TS];
#pragma unroll
            for (int j = 0; j < TS; j++) { qv[j] = sQ[ty * TS + j][kk]; kv[j] = sK[tx * TS + j][kk]; }
#pragma unroll
            for (int i = 0; i < TS; i++)
#pragma unroll
                for (int j = 0; j < TS; j++)
                    acc[i][j] = fmaf(qv[i], kv[j], acc[i][j]);
        }
        __syncthreads();
    }
    float* op = spart + (((size_t)(b * 4 + gi)) * NS_ + split) * MAXP_;
#pragma unroll
    for (int i = 0; i < TS; i++)
#pragma unroll
        for (int j = 0; j < TS; j++)
            op[(ty * TS + i) * G + tx * TS + j] = acc[i][j];
}

// reduce partials, scale by rq*rk*temp, softmax rows -> attn
__global__ __launch_bounds__(256) void softmax_k(const float* __restrict__ spart,
    const float* __restrict__ rqc, const float* __restrict__ rkc, const int* __restrict__ idxp,
    const float* __restrict__ temp, float* __restrict__ attn)
{
    const int gi = blockIdx.x, b = blockIdx.y;
    const int g = (gi == 0) ? 16 : (gi == 3 ? 48 : 32);
    const int start = (gi == 0) ? 0 : (gi == 1 ? 16 : (gi == 2 ? 48 : 80));
    __shared__ float S[MAXP_];
    __shared__ int sidx[48];
    if (threadIdx.x < g) sidx[threadIdx.x] = idxp[start + threadIdx.x];
    __syncthreads();
    const float tv = temp[gi];
    for (int p = threadIdx.x; p < g * g; p += 256) {
        float s = 0.f;
        const float* sp = spart + ((size_t)(b * 4 + gi)) * NS_ * MAXP_ + p;
        for (int k = 0; k < NS_; k++) s += sp[(size_t)k * MAXP_];
        int cc = p / g, dd = p - cc * g;
        S[p] = s * rqc[b * 128 + sidx[cc]] * rkc[b * 128 + sidx[dd]] * tv;
    }
    __syncthreads();
    const int wv = threadIdx.x >> 6, lane = threadIdx.x & 63;
    for (int r = wv; r < g; r += 4) {
        float val = (lane < g) ? S[r * g + lane] : -1e30f;
        float mx = val;
        for (int m = 32; m > 0; m >>= 1) mx = fmaxf(mx, __shfl_xor(mx, m));
        float e = (lane < g) ? expf(val - mx) : 0.f;
        float sum = e;
        for (int m = 32; m > 0; m >>= 1) sum += __shfl_xor(sum, m);
        if (lane < g) attn[((size_t)(b * 4 + gi)) * MAXP_ + r * g + lane] = e / sum;
    }
}

// ---------------------------------------------------------------------------
// attn @ v, emitting outallT / sxyT in [b][l][c] layout (c-fastest, coalesced)
// ---------------------------------------------------------------------------
template<int G>
__global__ __launch_bounds__(256) void av2_k(const float* __restrict__ dw, const int* __restrict__ idxp,
    const float* __restrict__ rqc, const float* __restrict__ rkc,
    const float* __restrict__ attn, int start, int gi,
    float* __restrict__ outallT, float* __restrict__ sxyT)
{
    constexpr int C4 = G / 4;
    constexpr int GP = G + 1;
    const int b = blockIdx.y;
    const int lB = blockIdx.x * 64;
    const int tid = threadIdx.x;
    __shared__ float sA[G * GP];
    __shared__ float sV[64][GP], sQ[64][GP], sK[64][GP];
    __shared__ int cv[G];
    __shared__ float rqs[G], rks[G];
    if (tid < G) {
        int c0 = idxp[start + tid];
        cv[tid] = c0;
        rqs[tid] = rqc[b * 128 + c0];
        rks[tid] = rkc[b * 128 + c0];
    }
    for (int p = tid; p < G * G; p += 256) {
        int cc = p / G, dd = p - cc * G;
        sA[cc * GP + dd] = attn[((size_t)(b * 4 + gi)) * MAXP_ + p];
    }
    __syncthreads();
    for (int idx = tid; idx < 64 * G; idx += 256) {
        int l = idx & 63, d = idx >> 6;
        size_t base = ((size_t)b * O3_ + cv[d]) * L_ + lB + l;
        sQ[l][d] = dw[base];
        sK[l][d] = dw[base + (size_t)128 * L_];
        sV[l][d] = dw[base + (size_t)256 * L_];
    }
    __syncthreads();
    const int strip = tid & 3, l = tid >> 2;
    float acc[C4];
#pragma unroll
    for (int j = 0; j < C4; j++) acc[j] = 0.f;
    for (int d = 0; d < G; d++) {
        float vd = sV[l][d];
#pragma unroll
        for (int j = 0; j < C4; j++)
            acc[j] = fmaf(sA[(strip * C4 + j) * GP + d], vd, acc[j]);
    }
    const size_t ob = ((size_t)b * L_ + lB + l) * C_ + start + strip * C4;
    float sv[C4];
#pragma unroll
    for (int j = 0; j < C4; j++) {
        int c = strip * C4 + j;
        sv[j] = acc[j] + rqs[c] * sQ[l][c] + rks[c] * sK[l][c];
    }
#pragma unroll
    for (int j = 0; j < C4; j += 4) {
        float4 o4 = {acc[j], acc[j + 1], acc[j + 2], acc[j + 3]};
        float4 s4 = {sv[j], sv[j + 1], sv[j + 2], sv[j + 3]};
        *reinterpret_cast<float4*>(&outallT[ob + j]) = o4;
        *reinterpret_cast<float4*>(&sxyT[ob + j]) = s4;
    }
}

// qv_cache = 0.9 * mean of tiled group means, broadcast over spatial
__global__ __launch_bounds__(256) void qvc_k(const float* __restrict__ gm, float* __restrict__ outq)
{
    const int cpos = blockIdx.x, b = blockIdx.y;
    const float* g = gm + b * 128;
    float v = g[cpos & 15] + g[16 + (cpos & 31)] + g[48 + (cpos & 31)];
    if (cpos < 96) v += g[80 + (cpos % 48)];
    v *= 0.225f; // 0.9 * (sum/4)
    float4 vv = {v, v, v, v};
    float4* op = reinterpret_cast<float4*>(outq + ((size_t)b * C_ + cpos) * L_);
    for (int i = threadIdx.x; i < L_ / 4; i += 256) op[i] = vv;
}

// ---------------------------------------------------------------------------
extern "C" void kernel_launch(void* const* d_in, const int* in_sizes, int n_in,
                              void* d_out, int out_size, void* d_ws, size_t ws_size,
                              hipStream_t stream)
{
    const float* x     = (const float*)d_in[0];
    const float* temp  = (const float*)d_in[1];
    const float* wqkv  = (const float*)d_in[2];
    const float* wdw   = (const float*)d_in[3];
    const float* wproj = (const float*)d_in[4];
    const float* wgate = (const float*)d_in[5];
    const float* bgate = (const float*)d_in[6];
    const float* wdown = (const float*)d_in[7];
    const float* bdown = (const float*)d_in[8];
    const float* wup   = (const float*)d_in[9];
    const float* bup   = (const float*)d_in[10];
    float* out = (float*)d_out;
    float* ws  = (float*)d_ws;

    // ws big buffers
    float* qkvCL  = ws;                       // [b][384][L]    [0, 50331648)
    float* xT     = ws + 50331648ull;         // [b][L][128]    (dead before dwCL write)
    float* dwCL   = ws + 50331648ull;         // [b][384][L]    [50331648, 100663296)
    float* outallT= ws;                       // [b][L][128]    (qkvCL dead)
    float* sxyT   = ws + 16777216ull;         // [b][L][128]
    float* gatedT = ws + 33554432ull;         // [b][L][128]
    float* mod1T  = ws + 16777216ull;         // [b][L][64]  (over sxyT, after gate)
    float* out2T  = ws + 25165824ull;         // [b][L][128] (over dead sxyT/gatedT)

    // small buffers + spart live in d_out first half until proj writes it
    float* spart = out;                       // 8*4*64*2304 = 4718592
    float* attn  = out + 4718592ull;          // 73728
    float* sumq  = out + 4800000ull;
    float* sumk  = out + 4801024ull;
    float* ssq   = out + 4802048ull;
    float* ssk   = out + 4803072ull;
    float* rqc   = out + 4804096ull;
    float* rkc   = out + 4805120ull;
    float* gm    = out + 4806144ull;
    int*   idxp  = (int*)(out + 4807168ull);

    // 1. transpose x -> xT [b][l][c]
    transp_k<<<dim3(512, 4, 8), 256, 0, stream>>>(x, xT);
    // 2. qkv GEMM (MFMA bf16x3), transposed store -> qkvCL [b][384][l]
    mgemm_k<128, 128, 4><<<dim3(128, 3, 8), 256, 0, stream>>>(wqkv, nullptr, xT, nullptr, qkvCL);
    // 3. depthwise 3x3 (overwrites xT region — xT is dead)
    dwconv_k<<<dim3(16, 384, 8), 256, 0, stream>>>(qkvCL, wdw, dwCL);
    // 4. per-(b,c) sums + combine/rank
    sums_k<<<dim3(128, 8), 256, 0, stream>>>(dwCL, sumq, sumk, ssq, ssk);
    combine_k<<<1, 128, 0, stream>>>(sumq, sumk, ssq, ssk, idxp, rqc, rkc, gm);
    // 5. attention scores (partials) per group
    score_k<16><<<dim3(NS_, 8), 256, 0, stream>>>(dwCL, idxp, 0, 0, spart);
    score_k<32><<<dim3(NS_, 8), 256, 0, stream>>>(dwCL, idxp, 16, 1, spart);
    score_k<32><<<dim3(NS_, 8), 256, 0, stream>>>(dwCL, idxp, 48, 2, spart);
    score_k<48><<<dim3(NS_, 8), 256, 0, stream>>>(dwCL, idxp, 80, 3, spart);
    // 6. reduce + softmax
    softmax_k<<<dim3(4, 8), 256, 0, stream>>>(spart, rqc, rkc, idxp, temp, attn);
    // 7. attn @ v -> outallT, sxyT in [l][c] layout
    av2_k<16><<<dim3(256, 8), 256, 0, stream>>>(dwCL, idxp, rqc, rkc, attn, 0, 0, outallT, sxyT);
    av2_k<32><<<dim3(256, 8), 256, 0, stream>>>(dwCL, idxp, rqc, rkc, attn, 16, 1, outallT, sxyT);
    av2_k<32><<<dim3(256, 8), 256, 0, stream>>>(dwCL, idxp, rqc, rkc, attn, 48, 2, outallT, sxyT);
    av2_k<48><<<dim3(256, 8), 256, 0, stream>>>(dwCL, idxp, rqc, rkc, attn, 80, 3, outallT, sxyT);
    // 8. gate GEMM (+gelu * sxy)
    mgemm_k<128, 128, 1><<<dim3(128, 1, 8), 256, 0, stream>>>(wgate, bgate, sxyT, sxyT, gatedT);
    // 9. qv_cache (reads gm from d_out first half, writes second half)
    qvc_k<<<dim3(128, 8), 256, 0, stream>>>(gm, out + 16777216ull);
    // 10. down GEMM (mod1T overwrites dead sxyT)
    mgemm_k<128, 64, 2><<<dim3(128, 1, 8), 256, 0, stream>>>(wdown, bdown, gatedT, nullptr, mod1T);
    // 11. up GEMM + residual
    mgemm_k<64, 128, 3><<<dim3(128, 1, 8), 256, 0, stream>>>(wup, bup, mod1T, outallT, out2T);
    // 12. proj GEMM -> final output (transposed store, overwrites smalls)
    mgemm_k<128, 128, 4><<<dim3(128, 1, 8), 256, 0, stream>>>(wproj, nullptr, out2T, nullptr, out);
}